// Round 21
// baseline (166.065 us; speedup 1.0000x reference)
//
#include <hip/hip_runtime.h>

#define B_   128
#define L_   196
#define ENC_ 2048
#define DEC_ 512
#define ATT_ 512
#define M_   (B_ * L_)   // 25088

typedef _Float16 f16x8 __attribute__((ext_vector_type(8)));
typedef __fp16   h16x2 __attribute__((ext_vector_type(2)));
typedef float    f32x4 __attribute__((ext_vector_type(4)));

// Raw barrier: order LDS ops (lgkmcnt) but do NOT drain vmcnt here.
#define FENCE_LDS_BARRIER()                                        \
    do {                                                           \
        asm volatile("s_waitcnt lgkmcnt(0)" ::: "memory");         \
        __builtin_amdgcn_s_barrier();                              \
        __builtin_amdgcn_sched_barrier(0);                         \
    } while (0)

__device__ __forceinline__ void gload16(const _Float16* g, _Float16* l) {
    __builtin_amdgcn_global_load_lds(
        (const __attribute__((address_space(1))) void*)g,
        (__attribute__((address_space(3))) void*)l, 16, 0, 0);
}

// ---------------- ws layout ----------------
// [0,        262144)  dec_map f32 [128][512]
// [262144,  2359296)  WeTs2   f16 tiled [nt2=2][kt=64][k8=4][col=256] x f16x8
// [2359296, 2559904)  scores  f32 [2][25088]

// We [2048][512] fp32 -> WeTs2 tiled f16. Unit (nt2,kt,k8,col) holds
// We[kt*32+k8*8+j][nt2*256+col], j=0..7. (Phase p of BK=64 reads kt=2p,2p+1
// = contiguous 2048 units -> DMA-friendly.)
__global__ void wets2_kernel(const float* __restrict__ We, _Float16* __restrict__ WeTs) {
    int u = blockIdx.x * 256 + threadIdx.x;     // 131072 units
    int col = u & 255;
    int k8  = (u >> 8) & 3;
    int kt  = (u >> 10) & 63;
    int nt  = u >> 16;
    int n  = nt * 256 + col;
    int k0 = kt * 32 + k8 * 8;
    f16x8 h;
#pragma unroll
    for (int j = 0; j < 8; ++j) h[j] = (_Float16)We[(k0 + j) * ATT_ + n];
    *reinterpret_cast<f16x8*>(WeTs + (size_t)u * 8) = h;
}

__global__ void decmap_kernel(const float* __restrict__ dh, const float* __restrict__ Wd,
                              const float* __restrict__ bd, float* __restrict__ dec) {
    int b = blockIdx.x;       // 128
    int a = threadIdx.x;      // 512
    float acc = bd[a];
    const float* dhp = dh + b * DEC_;
#pragma unroll 8
    for (int k = 0; k < DEC_; ++k) acc += dhp[k] * Wd[k * ATT_ + a];
    dec[b * ATT_ + a] = acc;
}

// Fused GEMM: 256x256 tile, BK=64, 32 phases (R8-R19 lesson: a barrier-phase
// costs ~2400cy regardless of contents -> halve the phase count, double the
// work per phase). Grid 196 <= 256 CUs, 1 block/CU (LDS 132KB), SINGLE round.
// 512 threads = 8 waves (2 wm x 4 wn), wave tile 128x64, acc 32 frags =
// 128 AGPR. A: ONE staging set (32 VGPR), loads at phase START, cvt+ds_write
// at phase END -> T14 slack = full phase (~2000cy > HBM latency). B: pure
// global_load_lds DMA (0 regs) from pre-tiled WeTs; writeA's reg-dependency
// drains only A loads; explicit vmcnt(0) before the fence lands on B issued
// a full phase earlier. launch_bounds(512,2): 2 waves/SIMD -> 256 regs/wave.
__global__ __launch_bounds__(512, 2)
void gemm_score_kernel(const float* __restrict__ enc,
                       const _Float16* __restrict__ WeTs,
                       const float* __restrict__ be,
                       const float* __restrict__ wa,
                       const float* __restrict__ dec,
                       float* __restrict__ scores) {
    __shared__ _Float16 As[2][16384];    // 32KB each: 2 sub-k32 x 1024 units
    __shared__ _Float16 Bs[2][16384];    // 32KB each: 2048 linear units
    __shared__ float red[4][256];

    // bijective XCD chunking for 196 blocks (196 = 8*24 + 4, m204 formula):
    // nt2-siblings of one mtile land on one XCD -> A slab L2-shared.
    int bid = blockIdx.x;
    int xcd = bid & 7, kk = bid >> 3;
    int sid = (xcd < 4 ? xcd * 25 : 100 + (xcd - 4) * 24) + kk;
    int mtile = sid >> 1;                            // 0..97
    int nt2   = sid & 1;                             // 0..1

    int tid  = threadIdx.x;
    int lane = tid & 63, wid = tid >> 6;             // 8 waves
    int wm = wid >> 2, wn = wid & 3;                 // 2 x 4; wave = 128x64
    int l15 = lane & 15, lg = lane >> 4;

    // A staging: thread -> row = tid>>1 (0..255), h = tid&1 (16 f32 per ks)
    int arow = tid >> 1;
    int h    = tid & 1;
    const float* ag = enc + (size_t)(mtile * 256 + arow) * ENC_ + h * 16;
    // write units (16B) within a sub-k32 tile: c8 = 2h, 2h+1; swizzled row
    int wu0 = (2 * h) * 256 + (arow ^ (4 * h));
    int wu1 = (2 * h + 1) * 256 + (arow ^ (4 * h + 2));

    // B DMA source: nt2 block = 65536 units; phase p = units [p*2048, +2048)
    const _Float16* bsrc = WeTs + (size_t)nt2 * 65536 * 8;

    // frag read offsets (halves)
    int aro0 = (lg * 256 + ((wm * 128 + l15) ^ (2 * lg))) * 8;  // + mi*128 + ks*8192
    int bfo  = (lg * 256 + wn * 64 + l15) * 8;                  // + ni*128 + ks*8192

    // ONE A staging register set (rule #20: static indexing via unroll)
    f32x4 areg[8];

    f32x4 acc[8][4];
#pragma unroll
    for (int mi = 0; mi < 8; ++mi)
#pragma unroll
        for (int ni = 0; ni < 4; ++ni) acc[mi][ni] = (f32x4){0.f, 0.f, 0.f, 0.f};

    auto loadA = [&](int p) {
        const float* a = ag + p * 64;
#pragma unroll
        for (int ks = 0; ks < 2; ++ks)
#pragma unroll
            for (int j = 0; j < 4; ++j)
                areg[ks * 4 + j] = *reinterpret_cast<const f32x4*>(a + ks * 32 + j * 4);
    };
    auto writeA = [&](int buf) {
        _Float16* Ap = As[buf];
#pragma unroll
        for (int ks = 0; ks < 2; ++ks) {
            union { h16x2 h2[4]; f16x8 h8; } cv;
            cv.h2[0] = __builtin_amdgcn_cvt_pkrtz(areg[ks * 4 + 0][0], areg[ks * 4 + 0][1]);
            cv.h2[1] = __builtin_amdgcn_cvt_pkrtz(areg[ks * 4 + 0][2], areg[ks * 4 + 0][3]);
            cv.h2[2] = __builtin_amdgcn_cvt_pkrtz(areg[ks * 4 + 1][0], areg[ks * 4 + 1][1]);
            cv.h2[3] = __builtin_amdgcn_cvt_pkrtz(areg[ks * 4 + 1][2], areg[ks * 4 + 1][3]);
            *reinterpret_cast<f16x8*>(Ap + (wu0 + ks * 1024) * 8) = cv.h8;
            cv.h2[0] = __builtin_amdgcn_cvt_pkrtz(areg[ks * 4 + 2][0], areg[ks * 4 + 2][1]);
            cv.h2[1] = __builtin_amdgcn_cvt_pkrtz(areg[ks * 4 + 2][2], areg[ks * 4 + 2][3]);
            cv.h2[2] = __builtin_amdgcn_cvt_pkrtz(areg[ks * 4 + 3][0], areg[ks * 4 + 3][1]);
            cv.h2[3] = __builtin_amdgcn_cvt_pkrtz(areg[ks * 4 + 3][2], areg[ks * 4 + 3][3]);
            *reinterpret_cast<f16x8*>(Ap + (wu1 + ks * 1024) * 8) = cv.h8;
        }
    };
    auto dmab = [&](int buf, int p) {
        const _Float16* s = bsrc + (size_t)p * 2048 * 8;
#pragma unroll
        for (int j = 0; j < 4; ++j)
            gload16(s + (j * 512 + tid) * 8, &Bs[buf][(j * 512 + tid) * 8]);
    };
    auto compute = [&](int buf) {
        const _Float16* Ap = As[buf];
        const _Float16* Bp = Bs[buf];
#pragma unroll
        for (int ks = 0; ks < 2; ++ks) {
            f16x8 af[8], bf[4];
#pragma unroll
            for (int mi = 0; mi < 8; ++mi)
                af[mi] = *reinterpret_cast<const f16x8*>(Ap + ks * 8192 + aro0 + mi * 128);
#pragma unroll
            for (int ni = 0; ni < 4; ++ni)
                bf[ni] = *reinterpret_cast<const f16x8*>(Bp + ks * 8192 + bfo + ni * 128);
            __builtin_amdgcn_s_setprio(1);
#pragma unroll
            for (int mi = 0; mi < 8; ++mi)
#pragma unroll
                for (int ni = 0; ni < 4; ++ni)
                    acc[mi][ni] = __builtin_amdgcn_mfma_f32_16x16x32_f16(
                        af[mi], bf[ni], acc[mi][ni], 0, 0, 0);
            __builtin_amdgcn_s_setprio(0);
        }
    };

    // prologue: tile 0 -> As[0], Bs[0]
    loadA(0);
    dmab(0, 0);
    writeA(0);                                       // reg-dep drains A loads
    asm volatile("s_waitcnt vmcnt(0)" ::: "memory"); // B(0) done
    FENCE_LDS_BARRIER();

    for (int p = 0; p < 32; ++p) {
        int pn = p + 1 < 32 ? p + 1 : 31;
        loadA(pn);                                   // issue-early (T14)
        dmab((p + 1) & 1, pn);                       // B DMA, 0 registers
        __builtin_amdgcn_sched_barrier(0);
        compute(p & 1);                              // 128 MFMA (2 sub-k)
        __builtin_amdgcn_sched_barrier(0);
        writeA((p + 1) & 1);                         // write-late; drains A only
        asm volatile("s_waitcnt vmcnt(0)" ::: "memory"); // B issued ~phase ago
        FENCE_LDS_BARRIER();
    }

    // Epilogue: x = acc + be[n] + dec[b][n]; rowsum += tanh(x)*wa[n]
    float rsum[8][4];
#pragma unroll
    for (int mi = 0; mi < 8; ++mi)
#pragma unroll
        for (int j = 0; j < 4; ++j) rsum[mi][j] = 0.f;

    int rb = mtile * 256 + wm * 128;
#pragma unroll
    for (int ni = 0; ni < 4; ++ni) {
        int n = nt2 * 256 + wn * 64 + ni * 16 + l15;
        float wav = wa[n];
        float bev = be[n];
#pragma unroll
        for (int mi = 0; mi < 8; ++mi) {
#pragma unroll
            for (int j = 0; j < 4; ++j) {
                int row = rb + mi * 16 + lg * 4 + j;    // C/D: col=lane&15, row=(lane>>4)*4+reg
                int b = row / L_;
                float x = acc[mi][ni][j] + bev + dec[b * ATT_ + n];
                float e = __expf(2.0f * x);
                float t = 1.0f - 2.0f / (e + 1.0f);     // tanh(x), inf-safe
                rsum[mi][j] += t * wav;
            }
        }
    }
#pragma unroll
    for (int mi = 0; mi < 8; ++mi) {
#pragma unroll
        for (int j = 0; j < 4; ++j) {
            float v = rsum[mi][j];
            v += __shfl_xor(v, 1);
            v += __shfl_xor(v, 2);
            v += __shfl_xor(v, 4);
            v += __shfl_xor(v, 8);
            if (l15 == 0) red[wn][wm * 128 + mi * 16 + lg * 4 + j] = v;
        }
    }
    __syncthreads();
    if (tid < 256)
        scores[(size_t)nt2 * M_ + mtile * 256 + tid] =
            red[0][tid] + red[1][tid] + red[2][tid] + red[3][tid];
}

// softmax over L per batch row; sums the 2 nt2 partials. ba cancels.
__global__ void softmax_kernel(const float* __restrict__ scores, float* __restrict__ alphas) {
    int b = blockIdx.x, t = threadIdx.x;     // 128 blocks x 256 threads
    int lane = t & 63, wid = t >> 6;
    __shared__ float red[4];
    float s = 0.f, val = -1e30f;
    if (t < L_) {
        int r = b * L_ + t;
        s = scores[r] + scores[M_ + r];
        val = s;
    }
    float m = val;
#pragma unroll
    for (int off = 1; off < 64; off <<= 1) m = fmaxf(m, __shfl_xor(m, off));
    if (lane == 0) red[wid] = m;
    __syncthreads();
    m = fmaxf(fmaxf(red[0], red[1]), fmaxf(red[2], red[3]));
    float e = (t < L_) ? __expf(s - m) : 0.f;
    float sum = e;
#pragma unroll
    for (int off = 1; off < 64; off <<= 1) sum += __shfl_xor(sum, off);
    __syncthreads();
    if (lane == 0) red[wid] = sum;
    __syncthreads();
    sum = red[0] + red[1] + red[2] + red[3];
    if (t < L_) alphas[b * L_ + t] = e / sum;
}

// context[b][e] = sum_l alphas[b][l] * enc[b][l][e]
__global__ void context_kernel(const float* __restrict__ enc, const float* __restrict__ alphas,
                               float* __restrict__ ctx) {
    int b = blockIdx.x >> 2;                  // 128 b x 4 e-chunks = 512 blocks
    int ec = blockIdx.x & 3;
    int e = ec * 512 + threadIdx.x * 2;
    const float* ep = enc + (size_t)b * L_ * ENC_ + e;
    const float* ap = alphas + b * L_;
    float ax = 0.f, ay = 0.f;
#pragma unroll 4
    for (int l = 0; l < L_; ++l) {
        float a = ap[l];
        float2 v = *reinterpret_cast<const float2*>(ep + (size_t)l * ENC_);
        ax += a * v.x;
        ay += a * v.y;
    }
    float2 r; r.x = ax; r.y = ay;
    *reinterpret_cast<float2*>(&ctx[b * ENC_ + e]) = r;
}

extern "C" void kernel_launch(void* const* d_in, const int* in_sizes, int n_in,
                              void* d_out, int out_size, void* d_ws, size_t ws_size,
                              hipStream_t stream) {
    const float* enc = (const float*)d_in[0];
    const float* dh  = (const float*)d_in[1];
    const float* We  = (const float*)d_in[2];
    const float* be  = (const float*)d_in[3];
    const float* Wd  = (const float*)d_in[4];
    const float* bd  = (const float*)d_in[5];
    const float* wa  = (const float*)d_in[6];
    // d_in[7] = ba: shifts all scores equally -> cancels in softmax, unused.

    float* out    = (float*)d_out;
    float* ctx    = out;               // [128][2048]
    float* alphas = out + B_ * ENC_;   // [128][196]

    char* ws = (char*)d_ws;
    float*    dec     = (float*)ws;                            // 256 KiB
    _Float16* WeTs2   = (_Float16*)(ws + 262144);              // 2 MiB
    float*    scores  = (float*)(ws + 2359296);                // 2 x 98 KiB

    hipLaunchKernelGGL(wets2_kernel,      dim3(512), dim3(256), 0, stream, We, WeTs2);
    hipLaunchKernelGGL(decmap_kernel,     dim3(128), dim3(512), 0, stream, dh, Wd, bd, dec);
    hipLaunchKernelGGL(gemm_score_kernel, dim3(196), dim3(512), 0, stream, enc, WeTs2, be, wa, dec, scores);
    hipLaunchKernelGGL(softmax_kernel,    dim3(128), dim3(256), 0, stream, scores, alphas);
    hipLaunchKernelGGL(context_kernel,    dim3(512), dim3(256), 0, stream, enc, alphas, ctx);
}

// Round 22
// 140.982 us; speedup vs baseline: 1.1779x; 1.1779x over previous
//
#include <hip/hip_runtime.h>

#define B_   128
#define L_   196
#define ENC_ 2048
#define DEC_ 512
#define ATT_ 512
#define M_   (B_ * L_)   // 25088

typedef _Float16 f16x8 __attribute__((ext_vector_type(8)));
typedef __fp16   h16x2 __attribute__((ext_vector_type(2)));
typedef float    f32x4 __attribute__((ext_vector_type(4)));

// Raw barrier: order LDS ops (lgkmcnt) but do NOT drain vmcnt.
#define FENCE_LDS_BARRIER()                                        \
    do {                                                           \
        asm volatile("s_waitcnt lgkmcnt(0)" ::: "memory");         \
        __builtin_amdgcn_s_barrier();                              \
        __builtin_amdgcn_sched_barrier(0);                         \
    } while (0)

__device__ __forceinline__ void gload16(const _Float16* g, _Float16* l) {
    __builtin_amdgcn_global_load_lds(
        (const __attribute__((address_space(1))) void*)g,
        (__attribute__((address_space(3))) void*)l, 16, 0, 0);
}

// ---------------- ws layout ----------------
// [0,        262144)  dec_map f32 [128][512]
// [262144,  2359296)  WeTs2   f16 tiled [nt2=2][kt=64][k8=4][col=256] x f16x8
// [2359296, 2559904)  scores  f32 [2][25088]

// We [2048][512] fp32 -> WeTs2 tiled f16. Unit (nt2,kt,k8,col) holds
// We[kt*32+k8*8+j][nt2*256+col], j=0..7.
__global__ void wets2_kernel(const float* __restrict__ We, _Float16* __restrict__ WeTs) {
    int u = blockIdx.x * 256 + threadIdx.x;     // 131072 units
    int col = u & 255;
    int k8  = (u >> 8) & 3;
    int kt  = (u >> 10) & 63;
    int nt  = u >> 16;
    int n  = nt * 256 + col;
    int k0 = kt * 32 + k8 * 8;
    f16x8 h;
#pragma unroll
    for (int j = 0; j < 8; ++j) h[j] = (_Float16)We[(k0 + j) * ATT_ + n];
    *reinterpret_cast<f16x8*>(WeTs + (size_t)u * 8) = h;
}

__global__ void decmap_kernel(const float* __restrict__ dh, const float* __restrict__ Wd,
                              const float* __restrict__ bd, float* __restrict__ dec) {
    int b = blockIdx.x;       // 128
    int a = threadIdx.x;      // 512
    float acc = bd[a];
    const float* dhp = dh + b * DEC_;
#pragma unroll 8
    for (int k = 0; k < DEC_; ++k) acc += dhp[k] * Wd[k * ATT_ + a];
    dec[b * ATT_ + a] = acc;
}

// Fused GEMM: 128x256 tile, BK=32, 256 threads (4 waves 2x2, wave=64x128).
// Grid 392 <= 512 slots at 2 blocks/CU -> SINGLE round. A crosses L2 2x.
// A: R8's reg-cvt staging (2 static sets, 2-ahead) into swizzled LDS dbuf.
// B: global_load_lds DMA, ONE ahead into buffer (k+1)%3. Buffer safety:
//    readers span phases k-1,k -> buffers (k-1)%3, k%3; DMA target (k+1)%3
//    distinct mod 3 (R19 staged 2-ahead = write/read collision = race).
// vmcnt discipline (in-order counts audited): phase k issues [B(k+1) x4,
// A(k+2) x4]. writeA(k)'s reg-dep drains last-phase A; explicit vmcnt(4)
// then drains exactly B(k+1) (issued a FULL phase earlier, L2-hot) while
// keeping this phase's 4 A loads in flight. (R19's vmcnt(6) drained 2
// same-phase A loads -> full HBM stall every phase.)
__global__ __launch_bounds__(256, 2)
void gemm_score_kernel(const float* __restrict__ enc,
                       const _Float16* __restrict__ WeTs,
                       const float* __restrict__ be,
                       const float* __restrict__ wa,
                       const float* __restrict__ dec,
                       float* __restrict__ scores) {
    __shared__ _Float16 As[2][4096];     // 8KB each
    __shared__ _Float16 Bs[3][8192];     // 16KB each
    __shared__ float red[2][128];

    // XCD swizzle: 392 = 8*49; the 2 ntile-siblings of one mtile share an XCD.
    int bid = blockIdx.x;
    int sid = (bid & 7) * 49 + (bid >> 3);           // bijective on [0,392)
    int mtile = sid >> 1;                            // 0..195
    int nt2   = sid & 1;                             // 0..1

    int tid  = threadIdx.x;
    int lane = tid & 63, wid = tid >> 6;
    int wm = wid >> 1, wn = wid & 1;                 // 2x2, wave = 64x128
    int l15 = lane & 15, lg = lane >> 4;

    // A staging: thread -> rows (tid>>2, +64), c8 = tid&3, 8 fp32 each
    int arowi = tid >> 2;
    int ac8   = tid & 3;
    const float* agA = enc + (size_t)(mtile * 128 + arowi) * ENC_ + ac8 * 8;
    const float* agB = agA + (size_t)64 * ENC_;
    int wa0 = (ac8 * 128 + (arowi ^ (2 * ac8))) * 8;
    int wa1 = wa0 + 64 * 8;

    // B DMA source: WeTs2 units (nt2, kt, p, col=tid); per-kt 8192 halves
    const _Float16* bsrc = WeTs + ((size_t)nt2 * 64 * 1024 + tid) * 8;

    // frag read half-offsets
    int afo = (lg * 128 + wm * 64 + (l15 ^ (2 * lg))) * 8;      // A swizzled
    int bfo = (lg * 256 + wn * 128 + l15) * 8;                  // B linear, +ni*128

    // A staging register sets — statically named (rule #20)
    float4 areg0[4], areg1[4];

    f32x4 acc[4][8];
#pragma unroll
    for (int mi = 0; mi < 4; ++mi)
#pragma unroll
        for (int ni = 0; ni < 8; ++ni) acc[mi][ni] = (f32x4){0.f, 0.f, 0.f, 0.f};

#define DEF_LOADA(S)                                                     \
    auto loadA##S = [&](int kt) {                                        \
        const float* a0 = agA + kt * 32;                                 \
        const float* a1 = agB + kt * 32;                                 \
        areg##S[0] = *reinterpret_cast<const float4*>(a0);               \
        areg##S[1] = *reinterpret_cast<const float4*>(a0 + 4);           \
        areg##S[2] = *reinterpret_cast<const float4*>(a1);               \
        areg##S[3] = *reinterpret_cast<const float4*>(a1 + 4);           \
    }
    DEF_LOADA(0); DEF_LOADA(1);
#undef DEF_LOADA

#define DEF_WRITEA(S)                                                    \
    auto writeA##S = [&](int buf) {                                      \
        _Float16* Ap = As[buf];                                          \
        union { h16x2 h2[4]; f16x8 h8; } cv;                             \
        cv.h2[0] = __builtin_amdgcn_cvt_pkrtz(areg##S[0].x, areg##S[0].y); \
        cv.h2[1] = __builtin_amdgcn_cvt_pkrtz(areg##S[0].z, areg##S[0].w); \
        cv.h2[2] = __builtin_amdgcn_cvt_pkrtz(areg##S[1].x, areg##S[1].y); \
        cv.h2[3] = __builtin_amdgcn_cvt_pkrtz(areg##S[1].z, areg##S[1].w); \
        *reinterpret_cast<f16x8*>(Ap + wa0) = cv.h8;                     \
        cv.h2[0] = __builtin_amdgcn_cvt_pkrtz(areg##S[2].x, areg##S[2].y); \
        cv.h2[1] = __builtin_amdgcn_cvt_pkrtz(areg##S[2].z, areg##S[2].w); \
        cv.h2[2] = __builtin_amdgcn_cvt_pkrtz(areg##S[3].x, areg##S[3].y); \
        cv.h2[3] = __builtin_amdgcn_cvt_pkrtz(areg##S[3].z, areg##S[3].w); \
        *reinterpret_cast<f16x8*>(Ap + wa1) = cv.h8;                     \
    }
    DEF_WRITEA(0); DEF_WRITEA(1);
#undef DEF_WRITEA

    // 4 DMA instructions stage one 32x256 f16 B tile
#define DMAB(BUF, KT)                                                    \
    do {                                                                 \
        const _Float16* s_ = bsrc + (size_t)(KT) * 8192;                 \
        gload16(s_,        &Bs[BUF][(0 * 256 + tid) * 8]);               \
        gload16(s_ + 2048, &Bs[BUF][(1 * 256 + tid) * 8]);               \
        gload16(s_ + 4096, &Bs[BUF][(2 * 256 + tid) * 8]);               \
        gload16(s_ + 6144, &Bs[BUF][(3 * 256 + tid) * 8]);               \
    } while (0)

#define COMPUTE(RA, RB)                                                  \
    do {                                                                 \
        f16x8 af[4], bf[8];                                              \
        _Pragma("unroll")                                                \
        for (int mi = 0; mi < 4; ++mi)                                   \
            af[mi] = *reinterpret_cast<const f16x8*>(&As[RA][afo + mi * 128]); \
        _Pragma("unroll")                                                \
        for (int ni = 0; ni < 8; ++ni)                                   \
            bf[ni] = *reinterpret_cast<const f16x8*>(&Bs[RB][bfo + ni * 128]); \
        __builtin_amdgcn_s_setprio(1);                                   \
        _Pragma("unroll")                                                \
        for (int mi = 0; mi < 4; ++mi)                                   \
            _Pragma("unroll")                                            \
            for (int ni = 0; ni < 8; ++ni)                               \
                acc[mi][ni] = __builtin_amdgcn_mfma_f32_16x16x32_f16(    \
                    af[mi], bf[ni], acc[mi][ni], 0, 0, 0);               \
        __builtin_amdgcn_s_setprio(0);                                   \
    } while (0)

    // Phase P(k): DMAB B(k+1)->Bs[(k+1)%3] FIRST; loadA(k+2); compute
    // (As[k%2], Bs[k%3]); writeA(k+1)->As[(k+1)%2] (reg-dep drains last-phase
    // A); vmcnt(4) drains B(k+1) only; lgkm fence.
#define PHASE(K, SA, RA, RB, DB, WS)                                     \
    do {                                                                 \
        int ka = (K) + 2 < 64 ? (K) + 2 : 63;                            \
        int kb = (K) + 1 < 64 ? (K) + 1 : 63;                            \
        DMAB(DB, kb);                                                    \
        __builtin_amdgcn_sched_barrier(0);                               \
        loadA##SA(ka);                                                   \
        __builtin_amdgcn_sched_barrier(0);                               \
        COMPUTE(RA, RB);                                                 \
        __builtin_amdgcn_sched_barrier(0);                               \
        writeA##WS(WS);                                                  \
        asm volatile("s_waitcnt vmcnt(4)" ::: "memory");                 \
        __builtin_amdgcn_sched_barrier(0);                               \
        FENCE_LDS_BARRIER();                                             \
    } while (0)

    // prologue: B(0)->Bs0; A tiles 0,1 -> sets 0,1; A(0)->As0; drain all
    DMAB(0, 0);
    __builtin_amdgcn_sched_barrier(0);
    loadA0(0);
    loadA1(1);
    writeA0(0);                      // reg-dep drains A(0),A(1) and B(0)
    asm volatile("s_waitcnt vmcnt(0)" ::: "memory");
    FENCE_LDS_BARRIER();

    // phase k: SA = k&1 (set for A(k+2)), RA = k&1, RB = k%3,
    //          DB = (k+1)%3, WS = (k+1)&1 (set loaded last phase = A(k+1))
    for (int k6 = 0; k6 < 10; ++k6) {
        int k = k6 * 6;
        PHASE(k + 0, 0, 0, 0, 1, 1);
        PHASE(k + 1, 1, 1, 1, 2, 0);
        PHASE(k + 2, 0, 0, 2, 0, 1);
        PHASE(k + 3, 1, 1, 0, 1, 0);
        PHASE(k + 4, 0, 0, 1, 2, 1);
        PHASE(k + 5, 1, 1, 2, 0, 0);
    }
    PHASE(60, 0, 0, 0, 1, 1);
    PHASE(61, 1, 1, 1, 2, 0);
    PHASE(62, 0, 0, 2, 0, 1);
    PHASE(63, 1, 1, 0, 1, 0);
#undef PHASE
#undef COMPUTE
#undef DMAB

    // Epilogue: x = acc + be[n] + dec[b][n]; rowsum += tanh(x)*wa[n]
    float rsum[4][4];
#pragma unroll
    for (int mi = 0; mi < 4; ++mi)
#pragma unroll
        for (int j = 0; j < 4; ++j) rsum[mi][j] = 0.f;

    int rb = mtile * 128 + wm * 64;
#pragma unroll
    for (int ni = 0; ni < 8; ++ni) {
        int n = nt2 * 256 + wn * 128 + ni * 16 + l15;
        float wav = wa[n];
        float bev = be[n];
#pragma unroll
        for (int mi = 0; mi < 4; ++mi) {
#pragma unroll
            for (int j = 0; j < 4; ++j) {
                int row = rb + mi * 16 + lg * 4 + j;    // C/D: col=lane&15, row=(lane>>4)*4+reg
                int b = row / L_;
                float x = acc[mi][ni][j] + bev + dec[b * ATT_ + n];
                float e = __expf(2.0f * x);
                float t = 1.0f - 2.0f / (e + 1.0f);     // tanh(x), inf-safe
                rsum[mi][j] += t * wav;
            }
        }
    }
#pragma unroll
    for (int mi = 0; mi < 4; ++mi) {
#pragma unroll
        for (int j = 0; j < 4; ++j) {
            float v = rsum[mi][j];
            v += __shfl_xor(v, 1);
            v += __shfl_xor(v, 2);
            v += __shfl_xor(v, 4);
            v += __shfl_xor(v, 8);
            if (l15 == 0) red[wn][wm * 64 + mi * 16 + lg * 4 + j] = v;
        }
    }
    __syncthreads();
    if (tid < 128)
        scores[(size_t)nt2 * M_ + mtile * 128 + tid] = red[0][tid] + red[1][tid];
}

// softmax over L per batch row; sums the 2 nt2 partials. ba cancels.
__global__ void softmax_kernel(const float* __restrict__ scores, float* __restrict__ alphas) {
    int b = blockIdx.x, t = threadIdx.x;     // 128 blocks x 256 threads
    int lane = t & 63, wid = t >> 6;
    __shared__ float red[4];
    float s = 0.f, val = -1e30f;
    if (t < L_) {
        int r = b * L_ + t;
        s = scores[r] + scores[M_ + r];
        val = s;
    }
    float m = val;
#pragma unroll
    for (int off = 1; off < 64; off <<= 1) m = fmaxf(m, __shfl_xor(m, off));
    if (lane == 0) red[wid] = m;
    __syncthreads();
    m = fmaxf(fmaxf(red[0], red[1]), fmaxf(red[2], red[3]));
    float e = (t < L_) ? __expf(s - m) : 0.f;
    float sum = e;
#pragma unroll
    for (int off = 1; off < 64; off <<= 1) sum += __shfl_xor(sum, off);
    __syncthreads();
    if (lane == 0) red[wid] = sum;
    __syncthreads();
    sum = red[0] + red[1] + red[2] + red[3];
    if (t < L_) alphas[b * L_ + t] = e / sum;
}

// context[b][e] = sum_l alphas[b][l] * enc[b][l][e]
__global__ void context_kernel(const float* __restrict__ enc, const float* __restrict__ alphas,
                               float* __restrict__ ctx) {
    int b = blockIdx.x >> 2;                  // 128 b x 4 e-chunks = 512 blocks
    int ec = blockIdx.x & 3;
    int e = ec * 512 + threadIdx.x * 2;
    const float* ep = enc + (size_t)b * L_ * ENC_ + e;
    const float* ap = alphas + b * L_;
    float ax = 0.f, ay = 0.f;
#pragma unroll 4
    for (int l = 0; l < L_; ++l) {
        float a = ap[l];
        float2 v = *reinterpret_cast<const float2*>(ep + (size_t)l * ENC_);
        ax += a * v.x;
        ay += a * v.y;
    }
    float2 r; r.x = ax; r.y = ay;
    *reinterpret_cast<float2*>(&ctx[b * ENC_ + e]) = r;
}

extern "C" void kernel_launch(void* const* d_in, const int* in_sizes, int n_in,
                              void* d_out, int out_size, void* d_ws, size_t ws_size,
                              hipStream_t stream) {
    const float* enc = (const float*)d_in[0];
    const float* dh  = (const float*)d_in[1];
    const float* We  = (const float*)d_in[2];
    const float* be  = (const float*)d_in[3];
    const float* Wd  = (const float*)d_in[4];
    const float* bd  = (const float*)d_in[5];
    const float* wa  = (const float*)d_in[6];
    // d_in[7] = ba: shifts all scores equally -> cancels in softmax, unused.

    float* out    = (float*)d_out;
    float* ctx    = out;               // [128][2048]
    float* alphas = out + B_ * ENC_;   // [128][196]

    char* ws = (char*)d_ws;
    float*    dec     = (float*)ws;                            // 256 KiB
    _Float16* WeTs2   = (_Float16*)(ws + 262144);              // 2 MiB
    float*    scores  = (float*)(ws + 2359296);                // 2 x 98 KiB

    hipLaunchKernelGGL(wets2_kernel,      dim3(512), dim3(256), 0, stream, We, WeTs2);
    hipLaunchKernelGGL(decmap_kernel,     dim3(128), dim3(512), 0, stream, dh, Wd, bd, dec);
    hipLaunchKernelGGL(gemm_score_kernel, dim3(392), dim3(256), 0, stream, enc, WeTs2, be, wa, dec, scores);
    hipLaunchKernelGGL(softmax_kernel,    dim3(128), dim3(256), 0, stream, scores, alphas);
    hipLaunchKernelGGL(context_kernel,    dim3(512), dim3(256), 0, stream, enc, alphas, ctx);
}